// Round 2
// baseline (131.427 us; speedup 1.0000x reference)
//
#include <hip/hip_runtime.h>

#define EPS 1e-5f

typedef _Float16 half8 __attribute__((ext_vector_type(8)));
typedef float f32x16 __attribute__((ext_vector_type(16)));

// ---------------------------------------------------------------------------
// prep: fold BN into weights/biases, transpose w1 halves, cast to fp16
// ---------------------------------------------------------------------------
__global__ void prep_kernel(
    const float* __restrict__ w1, const float* __restrict__ b1,
    const float* __restrict__ g1, const float* __restrict__ be1,
    const float* __restrict__ m1, const float* __restrict__ v1,
    const float* __restrict__ w2, const float* __restrict__ b2,
    const float* __restrict__ g2, const float* __restrict__ be2,
    const float* __restrict__ m2, const float* __restrict__ v2,
    const float* __restrict__ w3, const float* __restrict__ b3,
    const float* __restrict__ g3, const float* __restrict__ be3,
    const float* __restrict__ m3, const float* __restrict__ v3,
    const float* __restrict__ w4,
    float* __restrict__ wxT, float* __restrict__ wyT, float* __restrict__ hb,
    float* __restrict__ b2f, float* __restrict__ b3f,
    _Float16* __restrict__ w2h, _Float16* __restrict__ w3h, _Float16* __restrict__ w4h)
{
    int tid = blockIdx.x * blockDim.x + threadIdx.x;
    int nth = gridDim.x * blockDim.x;

    for (int idx = tid; idx < 128 * 512; idx += nth) {
        int f = idx >> 9, h = idx & 511;
        float a = g1[h] * rsqrtf(v1[h] + EPS);
        wxT[idx] = a * w1[h * 256 + f];
        wyT[idx] = a * w1[h * 256 + 128 + f];
    }
    for (int idx = tid; idx < 256 * 512; idx += nth) {
        int n = idx >> 9;
        float a = g2[n] * rsqrtf(v2[n] + EPS);
        w2h[idx] = (_Float16)(a * w2[idx]);
    }
    for (int idx = tid; idx < 128 * 256; idx += nth) {
        int n = idx >> 8;
        float a = g3[n] * rsqrtf(v3[n] + EPS);
        w3h[idx] = (_Float16)(a * w3[idx]);
    }
    for (int idx = tid; idx < 64 * 128; idx += nth) {
        w4h[idx] = (_Float16)w4[idx];
    }
    if (tid < 512) {
        float a = g1[tid] * rsqrtf(v1[tid] + EPS);
        hb[tid] = a * b1[tid] + be1[tid] - m1[tid] * a;
    } else if (tid < 768) {
        int n = tid - 512;
        float a = g2[n] * rsqrtf(v2[n] + EPS);
        b2f[n] = a * b2[n] + be2[n] - m2[n] * a;
    } else if (tid < 896) {
        int n = tid - 768;
        float a = g3[n] * rsqrtf(v3[n] + EPS);
        b3f[n] = a * b3[n] + be3[n] - m3[n] * a;
    }
}

// ---------------------------------------------------------------------------
// hxhy: hxh[b,i,h] = f16(x[b,i,:]·wxT[:,h] + hb[h]); hyh[b,j,h] = f16(y·wyT)
// 128 blocks x 256 threads; block = (b, 16-row group, half of h)
// ---------------------------------------------------------------------------
__global__ void hxhy_kernel(
    const float* __restrict__ x, const float* __restrict__ y,
    const float* __restrict__ wxT, const float* __restrict__ wyT,
    const float* __restrict__ hb,
    _Float16* __restrict__ hxh, _Float16* __restrict__ hyh)
{
    int bid = blockIdx.x;
    int hg = bid & 1;
    int rg = (bid >> 1) & 7;
    int b  = bid >> 4;
    int t  = threadIdx.x;
    int h  = hg * 256 + t;

    __shared__ float xs[16][128];
    __shared__ float ys[16][128];
    for (int u = t; u < 2048; u += 256) {
        int r = u >> 7, f = u & 127;
        size_t row = (size_t)(b * 128 + rg * 16 + r) * 128 + f;
        xs[r][f] = x[row];
        ys[r][f] = y[row];
    }
    __syncthreads();

    float ax[16], ay[16];
#pragma unroll
    for (int r = 0; r < 16; ++r) { ax[r] = 0.f; ay[r] = 0.f; }

    for (int f = 0; f < 128; ++f) {
        float wx = wxT[f * 512 + h];
        float wy = wyT[f * 512 + h];
#pragma unroll
        for (int r = 0; r < 16; ++r) {
            ax[r] = fmaf(xs[r][f], wx, ax[r]);
            ay[r] = fmaf(ys[r][f], wy, ay[r]);
        }
    }
    float hbv = hb[h];
#pragma unroll
    for (int r = 0; r < 16; ++r) {
        size_t o = (size_t)(b * 128 + rg * 16 + r) * 512 + h;
        hxh[o] = (_Float16)(ax[r] + hbv);
        hyh[o] = (_Float16)ay[r];
    }
}

// ---------------------------------------------------------------------------
// fused: one block per (b,i). M=128 (all j), 512->256->128->64 MLP with
// 32x32x16 f16 MFMA, then s=sum_j e, out[j]=e[j]·s. 512 threads = 8 waves.
// LDS 71168 B -> 2 blocks/CU.
// ---------------------------------------------------------------------------
__global__ __launch_bounds__(512, 4)
void fused_kernel(
    const _Float16* __restrict__ hxh, const _Float16* __restrict__ hyh,
    const _Float16* __restrict__ w2h, const _Float16* __restrict__ w3h,
    const _Float16* __restrict__ w4h,
    const float* __restrict__ b2f, const float* __restrict__ b3f,
    const float* __restrict__ b4,
    float* __restrict__ out)
{
    constexpr int LDK = 72;   // a1t/w2t row stride (halves), 144 B (16B-mult)
    constexpr int LD2 = 264;  // a2 row stride (halves), 528 B
    constexpr int LD3 = 136;  // a3 row stride (halves), 272 B
    constexpr int LDE = 68;   // es row stride (f32), 272 B

    __shared__ char smem[3584 + 67584] __attribute__((aligned(16)));
    _Float16* hxs = (_Float16*)smem;             // [512] f16   1024 B
    float* spart  = (float*)(smem + 1024);       // [8][64]     2048 B
    float* ss     = (float*)(smem + 3072);       // [64]         256 B
    char* R1 = smem + 3584;
    _Float16* a1t = (_Float16*)R1;               // [128][72]  18432 B (L2 phase)
    _Float16* w2t = (_Float16*)(R1 + 18432);     // [256][72]  36864 B (L2 phase)
    _Float16* a2  = (_Float16*)R1;               // [128][264] 67584 B (after L2)
    _Float16* a3  = (_Float16*)R1;               // [128][136] 34816 B (after L3)
    float*    es  = (float*)R1;                  // [128][68]  34816 B (after L4)

    const int b = blockIdx.x >> 7;
    const int i = blockIdx.x & 127;
    const int t = threadIdx.x;
    const int wid = t >> 6;
    const int l   = t & 63;
    const int l31 = l & 31;
    const int lh  = l >> 5;

    if (t < 64)
        *(half8*)(hxs + t * 8) = *(const half8*)(hxh + (size_t)(b * 128 + i) * 512 + t * 8);
    __syncthreads();

    const int wm = wid >> 2, wn = wid & 3;       // 2 x 4 wave grid (L2/L3)
    const size_t hyb = (size_t)b * 65536;

    // ---------------- layer 2: [128x512] @ [256x512]^T ----------------
    f32x16 acc2[2][2];
#pragma unroll
    for (int mt = 0; mt < 2; ++mt)
#pragma unroll
        for (int nt = 0; nt < 2; ++nt) acc2[mt][nt] = (f32x16)0.f;

    const int sj = t >> 2, sq = t & 3;           // a1 staging: row, 16-half chunk
    const int sn = t >> 1, sh = (t & 1) * 32;    // w2 staging: row, 32-half chunk

    for (int kt = 0; kt < 8; ++kt) {
        const int k0 = kt * 64;
        {   // stage a1 tile [128][64]: relu(hx + hy), packed f16 math
            const _Float16* hyp = hyh + hyb + (size_t)sj * 512 + k0 + sq * 16;
            half8 y0 = *(const half8*)hyp;
            half8 y1 = *(const half8*)(hyp + 8);
            half8 x0 = *(const half8*)(hxs + k0 + sq * 16);
            half8 x1 = *(const half8*)(hxs + k0 + sq * 16 + 8);
            half8 o0, o1;
#pragma unroll
            for (int c = 0; c < 8; ++c) {
                _Float16 v0 = (_Float16)(x0[c] + y0[c]);
                _Float16 v1 = (_Float16)(x1[c] + y1[c]);
                o0[c] = v0 > (_Float16)0.f ? v0 : (_Float16)0.f;
                o1[c] = v1 > (_Float16)0.f ? v1 : (_Float16)0.f;
            }
            *(half8*)(a1t + sj * LDK + sq * 16) = o0;
            *(half8*)(a1t + sj * LDK + sq * 16 + 8) = o1;
        }
        {   // stage w2 tile [256][64]
            const _Float16* wp = w2h + (size_t)sn * 512 + k0 + sh;
            _Float16* dp = w2t + sn * LDK + sh;
            *(half8*)(dp)      = *(const half8*)(wp);
            *(half8*)(dp + 8)  = *(const half8*)(wp + 8);
            *(half8*)(dp + 16) = *(const half8*)(wp + 16);
            *(half8*)(dp + 24) = *(const half8*)(wp + 24);
        }
        __syncthreads();
#pragma unroll
        for (int kc = 0; kc < 4; ++kc) {
            half8 af0 = *(const half8*)(a1t + (wm * 64 + l31) * LDK + kc * 16 + lh * 8);
            half8 af1 = *(const half8*)(a1t + (wm * 64 + 32 + l31) * LDK + kc * 16 + lh * 8);
            half8 bf0 = *(const half8*)(w2t + (wn * 64 + l31) * LDK + kc * 16 + lh * 8);
            half8 bf1 = *(const half8*)(w2t + (wn * 64 + 32 + l31) * LDK + kc * 16 + lh * 8);
            acc2[0][0] = __builtin_amdgcn_mfma_f32_32x32x16_f16(af0, bf0, acc2[0][0], 0, 0, 0);
            acc2[1][0] = __builtin_amdgcn_mfma_f32_32x32x16_f16(af1, bf0, acc2[1][0], 0, 0, 0);
            acc2[0][1] = __builtin_amdgcn_mfma_f32_32x32x16_f16(af0, bf1, acc2[0][1], 0, 0, 0);
            acc2[1][1] = __builtin_amdgcn_mfma_f32_32x32x16_f16(af1, bf1, acc2[1][1], 0, 0, 0);
        }
        __syncthreads();
    }
    // epilogue -> a2 (fp16, relu); aliases a1t/w2t (dead after last sync)
    {
        float bb0 = b2f[wn * 64 + l31];
        float bb1 = b2f[wn * 64 + 32 + l31];
#pragma unroll
        for (int mt = 0; mt < 2; ++mt)
#pragma unroll
            for (int r = 0; r < 16; ++r) {
                int m = wm * 64 + mt * 32 + (r & 3) + 8 * (r >> 2) + 4 * lh;
                a2[m * LD2 + wn * 64 + l31]      = (_Float16)fmaxf(acc2[mt][0][r] + bb0, 0.f);
                a2[m * LD2 + wn * 64 + 32 + l31] = (_Float16)fmaxf(acc2[mt][1][r] + bb1, 0.f);
            }
    }
    __syncthreads();

    // ---------------- layer 3: [128x256] @ [128x256]^T, B direct from L2 ----
    f32x16 acc3[2];
    acc3[0] = (f32x16)0.f; acc3[1] = (f32x16)0.f;
#pragma unroll 4
    for (int kc = 0; kc < 16; ++kc) {
        half8 bfr = *(const half8*)(w3h + (size_t)(wn * 32 + l31) * 256 + kc * 16 + lh * 8);
        half8 af0 = *(const half8*)(a2 + (wm * 64 + l31) * LD2 + kc * 16 + lh * 8);
        half8 af1 = *(const half8*)(a2 + (wm * 64 + 32 + l31) * LD2 + kc * 16 + lh * 8);
        acc3[0] = __builtin_amdgcn_mfma_f32_32x32x16_f16(af0, bfr, acc3[0], 0, 0, 0);
        acc3[1] = __builtin_amdgcn_mfma_f32_32x32x16_f16(af1, bfr, acc3[1], 0, 0, 0);
    }
    __syncthreads();
    {
        float b3v = b3f[wn * 32 + l31];
#pragma unroll
        for (int mt = 0; mt < 2; ++mt)
#pragma unroll
            for (int r = 0; r < 16; ++r) {
                int m = wm * 64 + mt * 32 + (r & 3) + 8 * (r >> 2) + 4 * lh;
                a3[m * LD3 + wn * 32 + l31] = (_Float16)fmaxf(acc3[mt][r] + b3v, 0.f);
            }
    }
    __syncthreads();

    // ---------------- layer 4: [128x128] @ [64x128]^T, regrid 4x2 ----------
    const int wm4 = wid >> 1, wn4 = wid & 1;
    f32x16 acc4 = (f32x16)0.f;
#pragma unroll
    for (int kc = 0; kc < 8; ++kc) {
        half8 afr = *(const half8*)(a3 + (wm4 * 32 + l31) * LD3 + kc * 16 + lh * 8);
        half8 bfr = *(const half8*)(w4h + (size_t)(wn4 * 32 + l31) * 128 + kc * 16 + lh * 8);
        acc4 = __builtin_amdgcn_mfma_f32_32x32x16_f16(afr, bfr, acc4, 0, 0, 0);
    }
    __syncthreads();
    {
        float b4v = b4[wn4 * 32 + l31];
#pragma unroll
        for (int r = 0; r < 16; ++r) {
            int m = wm4 * 32 + (r & 3) + 8 * (r >> 2) + 4 * lh;
            es[m * LDE + wn4 * 32 + l31] = acc4[r] + b4v;
        }
    }
    __syncthreads();

    // ---------------- s = sum_j e ; out[j] = sum_k e[j][k]*s[k] ------------
    {
        float sv = 0.f;
#pragma unroll
        for (int jj = 0; jj < 16; ++jj) sv += es[(wid + jj * 8) * LDE + l];
        spart[wid * 64 + l] = sv;
    }
    __syncthreads();
    if (t < 64) {
        float s2 = 0.f;
#pragma unroll
        for (int r = 0; r < 8; ++r) s2 += spart[r * 64 + t];
        ss[t] = s2;
    }
    __syncthreads();
    {
        const int j = t >> 2, q = t & 3;
        float p = 0.f;
#pragma unroll
        for (int c = 0; c < 16; ++c) {
            int k = q + 4 * c;               // k-interleaved: 2 lanes/bank
            p += es[j * LDE + k] * ss[k];
        }
        p += __shfl_xor(p, 1);
        p += __shfl_xor(p, 2);
        if (q == 0) out[(size_t)(b * 128 + i) * 128 + j] = p;
    }
}

// ---------------------------------------------------------------------------
extern "C" void kernel_launch(void* const* d_in, const int* in_sizes, int n_in,
                              void* d_out, int out_size, void* d_ws, size_t ws_size,
                              hipStream_t stream)
{
    (void)in_sizes; (void)n_in; (void)out_size; (void)ws_size;

    const float* x   = (const float*)d_in[0];
    const float* y   = (const float*)d_in[1];
    const float* w1  = (const float*)d_in[2];
    const float* b1  = (const float*)d_in[3];
    const float* g1  = (const float*)d_in[4];
    const float* be1 = (const float*)d_in[5];
    const float* m1  = (const float*)d_in[6];
    const float* v1  = (const float*)d_in[7];
    const float* w2  = (const float*)d_in[8];
    const float* b2  = (const float*)d_in[9];
    const float* g2  = (const float*)d_in[10];
    const float* be2 = (const float*)d_in[11];
    const float* m2  = (const float*)d_in[12];
    const float* v2  = (const float*)d_in[13];
    const float* w3  = (const float*)d_in[14];
    const float* b3  = (const float*)d_in[15];
    const float* g3  = (const float*)d_in[16];
    const float* be3 = (const float*)d_in[17];
    const float* m3  = (const float*)d_in[18];
    const float* v3  = (const float*)d_in[19];
    const float* w4  = (const float*)d_in[20];
    const float* b4  = (const float*)d_in[21];
    float* out = (float*)d_out;

    // workspace layout (~2.97 MB)
    float* wxT = (float*)d_ws;                 // 65536 f32
    float* wyT = wxT + 65536;                  // 65536 f32
    float* hb  = wyT + 65536;                  // 512
    float* b2f = hb + 512;                     // 256
    float* b3f = b2f + 256;                    // 128
    _Float16* w2h = (_Float16*)(b3f + 128);    // 131072 f16
    _Float16* w3h = w2h + 131072;              // 32768 f16
    _Float16* w4h = w3h + 32768;               // 8192 f16
    _Float16* hxh = w4h + 8192;                // 524288 f16
    _Float16* hyh = hxh + 524288;              // 524288 f16

    hipLaunchKernelGGL(prep_kernel, dim3(64), dim3(256), 0, stream,
                       w1, b1, g1, be1, m1, v1,
                       w2, b2, g2, be2, m2, v2,
                       w3, b3, g3, be3, m3, v3,
                       w4,
                       wxT, wyT, hb, b2f, b3f, w2h, w3h, w4h);

    hipLaunchKernelGGL(hxhy_kernel, dim3(128), dim3(256), 0, stream,
                       x, y, wxT, wyT, hb, hxh, hyh);

    hipLaunchKernelGGL(fused_kernel, dim3(1024), dim3(512), 0, stream,
                       hxh, hyh, w2h, w3h, w4h, b2f, b3f, b4, out);
}

// Round 4
// 73.864 us; speedup vs baseline: 1.7793x; 1.7793x over previous
//
#include <hip/hip_runtime.h>

#define EPS 1e-5f

typedef _Float16 half8 __attribute__((ext_vector_type(8)));
typedef _Float16 half4 __attribute__((ext_vector_type(4)));
typedef float f32x16 __attribute__((ext_vector_type(16)));
typedef float f32x4v __attribute__((ext_vector_type(4)));

// ---------------------------------------------------------------------------
// pre_kernel: blocks 0..255 = hxhy via MFMA (w1 consumed directly, alpha/bias
// folded in epilogue); blocks 256..319 = weight prep (BN-fold w2/w3, cast w4).
// ---------------------------------------------------------------------------
__global__ __launch_bounds__(256)
void pre_kernel(
    const float* __restrict__ x, const float* __restrict__ y,
    const float* __restrict__ w1, const float* __restrict__ b1,
    const float* __restrict__ g1, const float* __restrict__ be1,
    const float* __restrict__ m1, const float* __restrict__ v1,
    const float* __restrict__ w2, const float* __restrict__ b2,
    const float* __restrict__ g2, const float* __restrict__ be2,
    const float* __restrict__ m2, const float* __restrict__ v2,
    const float* __restrict__ w3, const float* __restrict__ b3,
    const float* __restrict__ g3, const float* __restrict__ be3,
    const float* __restrict__ m3, const float* __restrict__ v3,
    const float* __restrict__ w4,
    _Float16* __restrict__ hxh, _Float16* __restrict__ hyh,
    _Float16* __restrict__ w2h, _Float16* __restrict__ w3h,
    _Float16* __restrict__ w4h,
    float* __restrict__ b2f, float* __restrict__ b3f)
{
    const int t = threadIdx.x;

    if (blockIdx.x >= 256) {
        // ---------------- prep part ----------------
        int tid = (blockIdx.x - 256) * 256 + t;
        const int nth = 64 * 256;
        for (int idx = tid; idx < 256 * 512; idx += nth) {
            int n = idx >> 9;
            float a = g2[n] * rsqrtf(v2[n] + EPS);
            w2h[idx] = (_Float16)(a * w2[idx]);
        }
        for (int idx = tid; idx < 128 * 256; idx += nth) {
            int n = idx >> 8;
            float a = g3[n] * rsqrtf(v3[n] + EPS);
            w3h[idx] = (_Float16)(a * w3[idx]);
        }
        for (int idx = tid; idx < 64 * 128; idx += nth) {
            w4h[idx] = (_Float16)w4[idx];
        }
        if (tid < 256) {
            float a = g2[tid] * rsqrtf(v2[tid] + EPS);
            b2f[tid] = a * b2[tid] + be2[tid] - m2[tid] * a;
        } else if (tid < 384) {
            int n = tid - 256;
            float a = g3[n] * rsqrtf(v3[n] + EPS);
            b3f[n] = a * b3[n] + be3[n] - m3[n] * a;
        }
        return;
    }

    // ---------------- hxhy part ----------------
    // bid: rg = 32-row group (32), ng = 128-col group (4), which = x/y (2)
    const int rg = blockIdx.x & 31;
    const int ng = (blockIdx.x >> 5) & 3;
    const int which = blockIdx.x >> 7;

    constexpr int LDA = 136;  // 272 B row stride
    __shared__ _Float16 sh[32 * 136 + 128 * 136] __attribute__((aligned(16)));
    _Float16* xa = sh;                 // [32][136]
    _Float16* wb = sh + 32 * 136;      // [128][136]

    const int rowbase = rg * 32;
    const float* src = which ? y : x;

    // stage A: 32 rows x 128 f32 -> f16
#pragma unroll
    for (int p = 0; p < 4; ++p) {
        int c = p * 256 + t;               // 0..1023 float4-chunks
        int r = c >> 5, fo = (c & 31) * 4;
        f32x4v v = *(const f32x4v*)(src + (size_t)(rowbase + r) * 128 + fo);
        half4 h; h[0] = (_Float16)v[0]; h[1] = (_Float16)v[1];
        h[2] = (_Float16)v[2]; h[3] = (_Float16)v[3];
        *(half4*)(xa + r * LDA + fo) = h;
    }
    // stage B: 128 n-rows x 128 k f32 -> f16 (w1 row-major, k-offset by which)
#pragma unroll
    for (int p = 0; p < 16; ++p) {
        int c = p * 256 + t;               // 0..4095
        int n = c >> 5, fo = (c & 31) * 4;
        f32x4v v = *(const f32x4v*)(w1 + (size_t)(ng * 128 + n) * 256 + which * 128 + fo);
        half4 h; h[0] = (_Float16)v[0]; h[1] = (_Float16)v[1];
        h[2] = (_Float16)v[2]; h[3] = (_Float16)v[3];
        *(half4*)(wb + n * LDA + fo) = h;
    }
    __syncthreads();

    const int wid = t >> 6;
    const int l = t & 63;
    const int l31 = l & 31, lh = l >> 5;

    f32x16 acc = (f32x16)0.f;
#pragma unroll
    for (int kc = 0; kc < 8; ++kc) {
        half8 af = *(const half8*)(xa + l31 * LDA + kc * 16 + lh * 8);
        half8 bf = *(const half8*)(wb + (wid * 32 + l31) * LDA + kc * 16 + lh * 8);
        acc = __builtin_amdgcn_mfma_f32_32x32x16_f16(af, bf, acc, 0, 0, 0);
    }

    const int n = ng * 128 + wid * 32 + l31;
    float alpha = g1[n] * rsqrtf(v1[n] + EPS);
    float bias = which ? 0.f : (alpha * b1[n] + be1[n] - m1[n] * alpha);
    _Float16* dst = which ? hyh : hxh;
#pragma unroll
    for (int r = 0; r < 16; ++r) {
        int m = (r & 3) + 8 * (r >> 2) + 4 * lh;
        dst[(size_t)(rowbase + m) * 512 + n] = (_Float16)(alpha * acc[r] + bias);
    }
}

// ---------------------------------------------------------------------------
// fused: one block per (b,i). M=128 (all j), 512->256->128->64 MLP with
// 32x32x16 f16 MFMA, then s=sum_j e, out[j]=e[j]·s. 512 threads = 8 waves.
// L2 phase: K=32 double-buffered staging, 1 barrier per k-step, global loads
// issued before MFMA (latency hidden). LDS 71168 B -> 2 blocks/CU.
// ---------------------------------------------------------------------------
__global__ __launch_bounds__(512, 4)
void fused_kernel(
    const _Float16* __restrict__ hxh, const _Float16* __restrict__ hyh,
    const _Float16* __restrict__ w2h, const _Float16* __restrict__ w3h,
    const _Float16* __restrict__ w4h,
    const float* __restrict__ b2f, const float* __restrict__ b3f,
    const float* __restrict__ b4,
    float* __restrict__ out)
{
    constexpr int LDK = 40;   // K=32 staging row stride (halves), 80 B
    constexpr int LD2 = 264;  // a2 row stride (halves), 528 B
    constexpr int LD3 = 136;  // a3 row stride (halves), 272 B
    constexpr int LDE = 68;   // es row stride (f32), 272 B

    __shared__ char smem[3584 + 67584] __attribute__((aligned(16)));
    _Float16* hxs = (_Float16*)smem;             // [512] f16   1024 B
    float* spart  = (float*)(smem + 1024);       // [8][64]     2048 B
    float* ss     = (float*)(smem + 3072);       // [64]         256 B
    char* R1 = smem + 3584;
    _Float16* a1t0 = (_Float16*)R1;              // [128][40] 10240 B
    _Float16* w2t0 = (_Float16*)(R1 + 10240);    // [256][40] 20480 B
    _Float16* a1t1 = (_Float16*)(R1 + 30720);    // [128][40]
    _Float16* w2t1 = (_Float16*)(R1 + 40960);    // [256][40]  (ends at 61440)
    _Float16* a2  = (_Float16*)R1;               // [128][264] 67584 B (after L2)
    _Float16* a3  = (_Float16*)R1;               // [128][136] (after L3)
    float*    es  = (float*)R1;                  // [128][68]  (after L4)

    const int b = blockIdx.x >> 7;
    const int i = blockIdx.x & 127;
    const int t = threadIdx.x;
    const int wid = t >> 6;
    const int l   = t & 63;
    const int l31 = l & 31;
    const int lh  = l >> 5;

    if (t < 64)
        *(half8*)(hxs + t * 8) = *(const half8*)(hxh + (size_t)(b * 128 + i) * 512 + t * 8);
    __syncthreads();

    const int wm = wid >> 2, wn = wid & 3;       // 2 x 4 wave grid (L2/L3)
    const size_t hyb = (size_t)b * 65536;

    // ---------------- layer 2: [128x512] @ [256x512]^T ----------------
    f32x16 acc2[2][2];
#pragma unroll
    for (int mt = 0; mt < 2; ++mt)
#pragma unroll
        for (int nt = 0; nt < 2; ++nt) acc2[mt][nt] = (f32x16)0.f;

    const int sj = t >> 2, sq = t & 3;           // a1 staging: row, 8-half chunk
    const int wn0 = t >> 2, wc0 = t & 3;         // w2 staging item 0 (cid = t)
    const int wn1 = (t + 512) >> 2;              // w2 staging item 1

    half8 ra, rx, rw0, rw1;

    auto LOAD = [&](int kt) {
        const int k0 = kt * 32;
        ra  = *(const half8*)(hyh + hyb + (size_t)sj * 512 + k0 + sq * 8);
        rx  = *(const half8*)(hxs + k0 + sq * 8);
        rw0 = *(const half8*)(w2h + (size_t)wn0 * 512 + k0 + wc0 * 8);
        rw1 = *(const half8*)(w2h + (size_t)wn1 * 512 + k0 + wc0 * 8);
    };
    auto WRITE = [&](_Float16* A, _Float16* W) {
        half8 o;
#pragma unroll
        for (int c = 0; c < 8; ++c) {
            _Float16 v = (_Float16)(ra[c] + rx[c]);
            o[c] = v > (_Float16)0.f ? v : (_Float16)0.f;
        }
        *(half8*)(A + sj * LDK + sq * 8) = o;
        *(half8*)(W + wn0 * LDK + wc0 * 8) = rw0;
        *(half8*)(W + wn1 * LDK + wc0 * 8) = rw1;
    };
    auto MFMA2 = [&](const _Float16* A, const _Float16* W) {
#pragma unroll
        for (int kc = 0; kc < 2; ++kc) {
            half8 af0 = *(const half8*)(A + (wm * 64 + l31) * LDK + kc * 16 + lh * 8);
            half8 af1 = *(const half8*)(A + (wm * 64 + 32 + l31) * LDK + kc * 16 + lh * 8);
            half8 bf0 = *(const half8*)(W + (wn * 64 + l31) * LDK + kc * 16 + lh * 8);
            half8 bf1 = *(const half8*)(W + (wn * 64 + 32 + l31) * LDK + kc * 16 + lh * 8);
            acc2[0][0] = __builtin_amdgcn_mfma_f32_32x32x16_f16(af0, bf0, acc2[0][0], 0, 0, 0);
            acc2[1][0] = __builtin_amdgcn_mfma_f32_32x32x16_f16(af1, bf0, acc2[1][0], 0, 0, 0);
            acc2[0][1] = __builtin_amdgcn_mfma_f32_32x32x16_f16(af0, bf1, acc2[0][1], 0, 0, 0);
            acc2[1][1] = __builtin_amdgcn_mfma_f32_32x32x16_f16(af1, bf1, acc2[1][1], 0, 0, 0);
        }
    };

    LOAD(0);
    WRITE(a1t0, w2t0);
    __syncthreads();
#pragma unroll 2
    for (int kt = 0; kt < 16; ++kt) {
        const int cur = kt & 1;
        if (kt < 15) LOAD(kt + 1);
        MFMA2(cur ? a1t1 : a1t0, cur ? w2t1 : w2t0);
        if (kt < 15) WRITE(cur ? a1t0 : a1t1, cur ? w2t0 : w2t1);
        __syncthreads();
    }

    // epilogue -> a2 (fp16, relu); aliases staging bufs (dead after last sync)
    {
        float bb0 = b2f[wn * 64 + l31];
        float bb1 = b2f[wn * 64 + 32 + l31];
#pragma unroll
        for (int mt = 0; mt < 2; ++mt)
#pragma unroll
            for (int r = 0; r < 16; ++r) {
                int m = wm * 64 + mt * 32 + (r & 3) + 8 * (r >> 2) + 4 * lh;
                a2[m * LD2 + wn * 64 + l31]      = (_Float16)fmaxf(acc2[mt][0][r] + bb0, 0.f);
                a2[m * LD2 + wn * 64 + 32 + l31] = (_Float16)fmaxf(acc2[mt][1][r] + bb1, 0.f);
            }
    }
    __syncthreads();

    // ---------------- layer 3: [128x256] @ [128x256]^T, B direct from L2 ----
    f32x16 acc3[2];
    acc3[0] = (f32x16)0.f; acc3[1] = (f32x16)0.f;
#pragma unroll 8
    for (int kc = 0; kc < 16; ++kc) {
        half8 bfr = *(const half8*)(w3h + (size_t)(wn * 32 + l31) * 256 + kc * 16 + lh * 8);
        half8 af0 = *(const half8*)(a2 + (wm * 64 + l31) * LD2 + kc * 16 + lh * 8);
        half8 af1 = *(const half8*)(a2 + (wm * 64 + 32 + l31) * LD2 + kc * 16 + lh * 8);
        acc3[0] = __builtin_amdgcn_mfma_f32_32x32x16_f16(af0, bfr, acc3[0], 0, 0, 0);
        acc3[1] = __builtin_amdgcn_mfma_f32_32x32x16_f16(af1, bfr, acc3[1], 0, 0, 0);
    }
    __syncthreads();
    {
        float b3v = b3f[wn * 32 + l31];
#pragma unroll
        for (int mt = 0; mt < 2; ++mt)
#pragma unroll
            for (int r = 0; r < 16; ++r) {
                int m = wm * 64 + mt * 32 + (r & 3) + 8 * (r >> 2) + 4 * lh;
                a3[m * LD3 + wn * 32 + l31] = (_Float16)fmaxf(acc3[mt][r] + b3v, 0.f);
            }
    }
    __syncthreads();

    // ---------------- layer 4: [128x128] @ [64x128]^T, regrid 4x2 ----------
    const int wm4 = wid >> 1, wn4 = wid & 1;
    f32x16 acc4 = (f32x16)0.f;
#pragma unroll
    for (int kc = 0; kc < 8; ++kc) {
        half8 afr = *(const half8*)(a3 + (wm4 * 32 + l31) * LD3 + kc * 16 + lh * 8);
        half8 bfr = *(const half8*)(w4h + (size_t)(wn4 * 32 + l31) * 128 + kc * 16 + lh * 8);
        acc4 = __builtin_amdgcn_mfma_f32_32x32x16_f16(afr, bfr, acc4, 0, 0, 0);
    }
    __syncthreads();  // a3 reads done before es overwrites it
    {
        float b4v = b4[wn4 * 32 + l31];
#pragma unroll
        for (int r = 0; r < 16; ++r) {
            int m = wm4 * 32 + (r & 3) + 8 * (r >> 2) + 4 * lh;
            es[m * LDE + wn4 * 32 + l31] = acc4[r] + b4v;
        }
    }
    __syncthreads();

    // ---------------- s = sum_j e ; out[j] = sum_k e[j][k]*s[k] ------------
    {
        float sv = 0.f;
#pragma unroll
        for (int jj = 0; jj < 16; ++jj) sv += es[(wid + jj * 8) * LDE + l];
        spart[wid * 64 + l] = sv;
    }
    __syncthreads();
    if (t < 64) {
        float s2 = 0.f;
#pragma unroll
        for (int r = 0; r < 8; ++r) s2 += spart[r * 64 + t];
        ss[t] = s2;
    }
    __syncthreads();
    {
        const int j = t >> 2, q = t & 3;
        float p = 0.f;
#pragma unroll
        for (int c = 0; c < 16; ++c) {
            int k = q + 4 * c;               // k-interleaved: 2 lanes/bank
            p += es[j * LDE + k] * ss[k];
        }
        p += __shfl_xor(p, 1);
        p += __shfl_xor(p, 2);
        if (q == 0) out[(size_t)(b * 128 + i) * 128 + j] = p;
    }
}

// ---------------------------------------------------------------------------
extern "C" void kernel_launch(void* const* d_in, const int* in_sizes, int n_in,
                              void* d_out, int out_size, void* d_ws, size_t ws_size,
                              hipStream_t stream)
{
    (void)in_sizes; (void)n_in; (void)out_size; (void)ws_size;

    const float* x   = (const float*)d_in[0];
    const float* y   = (const float*)d_in[1];
    const float* w1  = (const float*)d_in[2];
    const float* b1  = (const float*)d_in[3];
    const float* g1  = (const float*)d_in[4];
    const float* be1 = (const float*)d_in[5];
    const float* m1  = (const float*)d_in[6];
    const float* v1  = (const float*)d_in[7];
    const float* w2  = (const float*)d_in[8];
    const float* b2  = (const float*)d_in[9];
    const float* g2  = (const float*)d_in[10];
    const float* be2 = (const float*)d_in[11];
    const float* m2  = (const float*)d_in[12];
    const float* v2  = (const float*)d_in[13];
    const float* w3  = (const float*)d_in[14];
    const float* b3  = (const float*)d_in[15];
    const float* g3  = (const float*)d_in[16];
    const float* be3 = (const float*)d_in[17];
    const float* m3  = (const float*)d_in[18];
    const float* v3  = (const float*)d_in[19];
    const float* w4  = (const float*)d_in[20];
    const float* b4  = (const float*)d_in[21];
    float* out = (float*)d_out;

    // workspace layout (~2.44 MB)
    float* b2f = (float*)d_ws;                 // 256 f32
    float* b3f = b2f + 256;                    // 128 f32 (+pad to 16B ok)
    _Float16* w2h = (_Float16*)(b3f + 128);    // 131072 f16
    _Float16* w3h = w2h + 131072;              // 32768 f16
    _Float16* w4h = w3h + 32768;               // 8192 f16
    _Float16* hxh = w4h + 8192;                // 524288 f16
    _Float16* hyh = hxh + 524288;              // 524288 f16

    hipLaunchKernelGGL(pre_kernel, dim3(320), dim3(256), 0, stream,
                       x, y, w1, b1, g1, be1, m1, v1,
                       w2, b2, g2, be2, m2, v2,
                       w3, b3, g3, be3, m3, v3,
                       w4,
                       hxh, hyh, w2h, w3h, w4h, b2f, b3f);

    hipLaunchKernelGGL(fused_kernel, dim3(1024), dim3(512), 0, stream,
                       hxh, hyh, w2h, w3h, w4h, b2f, b3f, b4, out);
}